// Round 8
// baseline (37.202 us; speedup 1.0000x reference)
//
#include <hip/hip_runtime.h>
#include <hip/hip_bf16.h>

// MCorrLCorr via bf16 MFMA GEMM, per (b,hx) block (512 blocks, 2/CU), BARRIER-FREE:
//   out[b,o,hx,hy] = sum_{c,fx,fy} in[b,c,(hx+1)(fx+1)-1, 2hy+fy-2] * w[o,c,fx,fy] + bias[o]
// GEMM: C[o,hy] = A[o,k]*B[k,hy], k = c*32+fx*8+fy (K=1024).
// 8 waves = 2 o-halves x 4 hy-quarters (32o x 48hy per wave, mt2/tt3), full K per wave.
// NEW: zero __syncthreads in the whole kernel. Each wave stages its OWN 16-row x
// 112-float gy-window (gy in [96*whq-8, +112)) into a PRIVATE LDS strip, converts,
// and consumes it. Waves free-run and drift -> HBM/LDS/MFMA latencies overlap across
// 16 independent wave streams instead of serializing at 2 barriers/iter (R0-R7 all
// shared-staging + barriers and all landed 32.7-34.0 regardless of schedule).
// A: per-iter reg fragments from prepped wl[] (L2-hot), pinned BEFORE X loads so
// A-consumption waits vmcnt(7) and the 1-deep X prefetch stays in flight.

#define Bb   16
#define NGX  128
#define NGY  384
#define Oo   64
#define NHX  32
#define NHY  190

#define RSW   124                // strip row stride in shorts (248 B: 8B-aligned rows)
#define RDW   62                 // strip row stride in dwords
#define STRIP (16 * RSW)         // shorts per buf per wave (16 rows); 2 buf x 8 waves = 63.5 KB

typedef short bf16x8 __attribute__((ext_vector_type(8)));
typedef float f32x4  __attribute__((ext_vector_type(4)));
typedef unsigned short u16x4 __attribute__((ext_vector_type(4)));

__device__ __forceinline__ unsigned short f2bf(float f) {
  __hip_bfloat16 h = __float2bfloat16(f);
  return __builtin_bit_cast(unsigned short, h);
}

// wl[(k>>3)*512 + o*8 + (k&7)] = bf16(w[o*1024 + k])
__global__ void wprep_kernel(const float* __restrict__ w, unsigned short* __restrict__ wl) {
  int idx = blockIdx.x * 256 + threadIdx.x;
  int k8 = idx >> 9;             // k/8: 0..127
  int o  = (idx >> 3) & 63;
  int j  = idx & 7;
  wl[idx] = f2bf(w[o * 1024 + k8 * 8 + j]);
}

__global__ __launch_bounds__(512, 4)
void mcorr_mfma_kernel(const float* __restrict__ in, const unsigned short* __restrict__ wl,
                       const float* __restrict__ bias, float* __restrict__ out) {
  const int tid  = threadIdx.x;
  const int l    = tid & 63;
  const int wv   = tid >> 6;          // 8 waves
  const int wo   = wv >> 2;           // o half: o in [32*wo, 32*wo+32)
  const int whq  = wv & 3;            // hy quarter: hy in [48*whq, 48*whq+48)
  const int lo16 = l & 15, gq = l >> 4;

  // XCD swizzle: XCD x gets 2 consecutive b's worth of blocks (all hx -> L2 row reuse)
  int lid = blockIdx.x + NHX * blockIdx.y;
  int swz = (lid & 7) * 64 + (lid >> 3);
  const int hx = swz & 31;
  const int b  = swz >> 5;

  __shared__ __align__(16) unsigned short xs_[8 * 2 * STRIP];   // 63.5 KB

  f32x4 acc[2][3];
  #pragma unroll
  for (int i = 0; i < 2; ++i)
    #pragma unroll
    for (int j = 0; j < 3; ++j) acc[i][j] = (f32x4){0.f, 0.f, 0.f, 0.f};

  // per-wave private strip: [2 buf][16 rows][124 shorts]; row = (c_local, fx)
  unsigned short* wstrip = xs_ + wv * 2 * STRIP;

  // staging lane roles: 4 lanes per row, 7 float4 slots each (28 f4 = 112 floats/row)
  const int row  = l >> 2;
  const int q    = l & 3;
  const int c_lo = row >> 2;                               // c_local 0..3
  const int fx   = row & 3;
  const int gx   = (hx + 1) * (fx + 1) - 1;                // always in [0, NGX)
  // wave's gy window: [96*whq - 8, 96*whq + 104); load start clamped to row
  const int sgy  = (whq == 0) ? 0 : 96 * whq - 8;          // mult of 4 -> f4 aligned
  const int nf4  = (whq == 1 || whq == 2) ? 28 : 26;       // edge waves load 104 floats
  const int d0s  = (whq == 0) ? 8 : 0;                     // dest short offset of first load
  const float* src = in + (((size_t)b * 32 + c_lo) * NGX + gx) * NGY + sgy;
  const size_t cstep = (size_t)4 * NGX * NGY;              // +4 c per iter

  // zero border shorts once (left pad gy<0 for whq0; right pad gy>=384 for whq3)
  if (whq == 0 || whq == 3) {
    int zb = (whq == 0) ? 0 : 104;
    #pragma unroll
    for (int bu = 0; bu < 2; ++bu)
      *(unsigned*)&wstrip[bu * STRIP + row * RSW + zb + 2 * q] = 0;
  }

  float4 xv[7];                                            // 1-deep prefetch

#define WLOAD(T) do {                                                    \
    const float* s_ = src + (size_t)(T) * cstep;                         \
    _Pragma("unroll") for (int s2 = 0; s2 < 7; ++s2) {                   \
      int i4 = q + 4 * s2;                                               \
      if (i4 < nf4) xv[s2] = *(const float4*)(s_ + 4 * i4);              \
    }                                                                    \
  } while (0)

#define WCOMMIT(T) do {                                                  \
    unsigned short* d_ = wstrip + ((T) & 1) * STRIP + row * RSW + d0s;   \
    _Pragma("unroll") for (int s2 = 0; s2 < 7; ++s2) {                   \
      int i4 = q + 4 * s2;                                               \
      if (i4 < nf4) {                                                    \
        u16x4 h_;                                                        \
        h_[0] = f2bf(xv[s2].x); h_[1] = f2bf(xv[s2].y);                  \
        h_[2] = f2bf(xv[s2].z); h_[3] = f2bf(xv[s2].w);                  \
        *(u16x4*)&d_[4 * i4] = h_;                                       \
      }                                                                  \
    }                                                                    \
  } while (0)

  // B-frag (lane lo16,gq; subtile cs,tt): bf16 gy values [2*hy-2 .. 2*hy+5],
  // hy = 48*whq+16*tt+lo16 -> strip-local value v = 32*tt + 2*lo16 + 6 + j
  // -> dwords [r*62 + 3 + 16*tt + lo16, +4), r = 4*cs + gq (c_local=cs, fx=gq).
#define COMPUTE(T) do {                                                              \
    const unsigned* Xb_ = (const unsigned*)(wstrip + ((T) & 1) * STRIP);             \
    _Pragma("unroll") for (int cs_ = 0; cs_ < 4; ++cs_) {                            \
      const int r_ = cs_ * 4 + gq;                                                   \
      _Pragma("unroll") for (int tt_ = 0; tt_ < 3; ++tt_) {                          \
        const unsigned* xp_ = &Xb_[r_ * RDW + 3 + 16 * tt_ + lo16];                  \
        union { unsigned u[4]; bf16x8 v; } bb_;                                      \
        bb_.u[0] = xp_[0]; bb_.u[1] = xp_[1];                                        \
        bb_.u[2] = xp_[2]; bb_.u[3] = xp_[3];                                        \
        acc[0][tt_] = __builtin_amdgcn_mfma_f32_16x16x32_bf16(                       \
            a_[cs_][0], bb_.v, acc[0][tt_], 0, 0, 0);                                \
        acc[1][tt_] = __builtin_amdgcn_mfma_f32_16x16x32_bf16(                       \
            a_[cs_][1], bb_.v, acc[1][tt_], 0, 0, 0);                                \
      }                                                                              \
    }                                                                                \
  } while (0)

  // ---- prologue: stage iteration 0 into own strip (no sync with anyone) ----
  WLOAD(0);
  WCOMMIT(0);

  // ---- main loop: 8 iterations, ZERO barriers ----
  #pragma unroll
  for (int t = 0; t < 8; ++t) {
    // A-frags for THIS iteration, issued FIRST: consuming them waits vmcnt(7),
    // leaving the X loads of t+1 (issued next) in flight across the compute.
    bf16x8 a_[4][2];
    #pragma unroll
    for (int cs_ = 0; cs_ < 4; ++cs_) {
      const unsigned short* ap_ =
          wl + ((4 * t + cs_) * 4 + gq) * 512 + (32 * wo + lo16) * 8;
      a_[cs_][0] = *(const bf16x8*)ap_;
      a_[cs_][1] = *(const bf16x8*)(ap_ + 128);   // +16 o
    }
    __builtin_amdgcn_sched_barrier(0);
    if (t < 7) WLOAD(t + 1);             // HBM loads fly during COMPUTE(t)
    __builtin_amdgcn_sched_barrier(0);
    COMPUTE(t);                          // private ds_reads + MFMA
    if (t < 7) WCOMMIT(t + 1);           // waits own X loads (a full compute of slack)
  }

  // ---- epilogue: bias + store ----
  #pragma unroll
  for (int mt = 0; mt < 2; ++mt) {
    #pragma unroll
    for (int reg = 0; reg < 4; ++reg) {
      int o = 32 * wo + 16 * mt + 4 * gq + reg;
      float bv = bias[o];
      #pragma unroll
      for (int tt = 0; tt < 3; ++tt) {
        int hy = 48 * whq + 16 * tt + lo16;
        if (hy < NHY)
          out[(((size_t)b * Oo + o) * NHX + hx) * NHY + hy] = acc[mt][tt][reg] + bv;
      }
    }
  }
}

extern "C" void kernel_launch(void* const* d_in, const int* in_sizes, int n_in,
                              void* d_out, int out_size, void* d_ws, size_t ws_size,
                              hipStream_t stream) {
  const float* in   = (const float*)d_in[0];
  const float* w    = (const float*)d_in[1];
  const float* bias = (const float*)d_in[2];
  float* out = (float*)d_out;
  unsigned short* wl = (unsigned short*)d_ws;   // 128 KB scratch

  wprep_kernel<<<Oo * 1024 / 256, 256, 0, stream>>>(w, wl);

  dim3 grid(NHX, Bb);
  mcorr_mfma_kernel<<<grid, 512, 0, stream>>>(in, wl, bias, out);
}